// Round 1
// baseline (878.458 us; speedup 1.0000x reference)
//
#include <hip/hip_runtime.h>
#include <math.h>

#define N_NODES 50000
#define N_EDGES 800000
#define D_IN    128
#define ED_IN   64
#define HU      128   // H*U
#define NH      4
#define UD      32

#define NPB 8   // nodes per block in qkv kernel
#define EPB 8   // edges per block in score kernel

// K1: q/k/v = x @ W + b for all nodes. 128 threads, NPB nodes per block.
__global__ __launch_bounds__(128) void qkv_kernel(
    const float* __restrict__ x,
    const float* __restrict__ Wq, const float* __restrict__ bq,
    const float* __restrict__ Wk, const float* __restrict__ bk,
    const float* __restrict__ Wv, const float* __restrict__ bv,
    float* __restrict__ q, float* __restrict__ k, float* __restrict__ v) {
  const int base = blockIdx.x * NPB;
  const int t = threadIdx.x;
  __shared__ float xs[NPB][D_IN];
  for (int j = 0; j < NPB; ++j)
    xs[j][t] = x[(long)(base + j) * D_IN + t];
  __syncthreads();
  float aq[NPB], ak[NPB], av[NPB];
  const float bqt = bq[t], bkt = bk[t], bvt = bv[t];
  for (int j = 0; j < NPB; ++j) { aq[j] = bqt; ak[j] = bkt; av[j] = bvt; }
  for (int i = 0; i < D_IN; ++i) {
    const float wq = Wq[i * HU + t];
    const float wk = Wk[i * HU + t];
    const float wv = Wv[i * HU + t];
    for (int j = 0; j < NPB; ++j) {
      const float xi = xs[j][i];
      aq[j] += xi * wq; ak[j] += xi * wk; av[j] += xi * wv;
    }
  }
  for (int j = 0; j < NPB; ++j) {
    const long o = (long)(base + j) * HU + t;
    q[o] = aq[j]; k[o] = ak[j]; v[o] = av[j];
  }
}

// K2: per-edge scores[e,h] = sum_u (q[src,h,u] + eh[e,h,u]) * k[dst,h,u]
// where eh = edge_features @ We + be. 128 threads, EPB edges per block.
__global__ __launch_bounds__(128) void score_kernel(
    const float* __restrict__ ef,
    const int* __restrict__ src, const int* __restrict__ dst,
    const float* __restrict__ We, const float* __restrict__ be,
    const float* __restrict__ q, const float* __restrict__ k,
    float* __restrict__ scores) {
  const long base = (long)blockIdx.x * EPB;
  const int t = threadIdx.x;
  __shared__ float efs[EPB][ED_IN];
  // load EPB rows of 64 floats with 128 threads: 2 rows per pass
  for (int r = 0; r < EPB; r += 2) {
    const int row = r + (t >> 6);
    const int col = t & 63;
    efs[row][col] = ef[(base + row) * ED_IN + col];
  }
  __syncthreads();
  float eh[EPB];
  const float bet = be[t];
  for (int j = 0; j < EPB; ++j) eh[j] = bet;
  for (int i = 0; i < ED_IN; ++i) {
    const float w = We[i * HU + t];
    for (int j = 0; j < EPB; ++j) eh[j] += efs[j][i] * w;
  }
  for (int j = 0; j < EPB; ++j) {
    const long e = base + j;
    const int s = src[e], d = dst[e];
    float p = (q[(long)s * HU + t] + eh[j]) * k[(long)d * HU + t];
    for (int off = 16; off > 0; off >>= 1) p += __shfl_down(p, off, 32);
    if ((t & 31) == 0) scores[e * NH + (t >> 5)] = p;
  }
}

// K3: per-node segmented softmax + attn*v[dst] aggregation + output GEMM + relu.
// One block of 128 threads per node; thread t -> (h = t/32, u = t%32).
__global__ __launch_bounds__(128) void aggregate_kernel(
    const int* __restrict__ src, const int* __restrict__ dst,
    const float* __restrict__ scores, const float* __restrict__ v,
    const float* __restrict__ Wo, const float* __restrict__ bo,
    float* __restrict__ out) {
  const int n = blockIdx.x;
  const int t = threadIdx.x;
  const int h = t >> 5, u = t & 31;

  // binary search: start = lower_bound(src, n), end = lower_bound(src, n+1)
  int lo = 0, hi = N_EDGES;
  while (lo < hi) { const int mid = (lo + hi) >> 1; if (src[mid] < n) lo = mid + 1; else hi = mid; }
  const int start = lo;
  hi = N_EDGES;
  while (lo < hi) { const int mid = (lo + hi) >> 1; if (src[mid] < n + 1) lo = mid + 1; else hi = mid; }
  const int end = lo;

  // per-head max over segment (32 lanes of this head cooperate)
  float m = -INFINITY;
  for (int e = start + u; e < end; e += 32) m = fmaxf(m, scores[(long)e * NH + h]);
  for (int off = 16; off > 0; off >>= 1) m = fmaxf(m, __shfl_down(m, off, 32));
  m = __shfl(m, 0, 32);

  // per-head sum of exp
  float ssum = 0.f;
  for (int e = start + u; e < end; e += 32) ssum += expf(scores[(long)e * NH + h] - m);
  for (int off = 16; off > 0; off >>= 1) ssum += __shfl_down(ssum, off, 32);
  ssum = __shfl(ssum, 0, 32);
  const float inv = (end > start) ? 1.f / ssum : 0.f;

  // attended[h,u] = sum_e softmax(e,h) * v[dst[e],h,u]
  float acc = 0.f;
  for (int e = start; e < end; ++e) {
    const float w = expf(scores[(long)e * NH + h] - m);
    acc += w * v[(long)dst[e] * HU + t];
  }
  acc *= inv;

  __shared__ float att[HU];
  att[t] = acc;
  __syncthreads();

  // out[n,:] = relu(att @ Wo + bo), Wo is [128,32] row-major
  if (t < UD) {
    float o = bo[t];
    for (int i = 0; i < HU; ++i) o += att[i] * Wo[i * UD + t];
    out[(long)n * UD + t] = fmaxf(o, 0.f);
  }
}

extern "C" void kernel_launch(void* const* d_in, const int* in_sizes, int n_in,
                              void* d_out, int out_size, void* d_ws, size_t ws_size,
                              hipStream_t stream) {
  const float* x  = (const float*)d_in[0];
  const int*   ei = (const int*)d_in[1];
  const float* ef = (const float*)d_in[2];
  const float* Wq = (const float*)d_in[3];
  const float* bq = (const float*)d_in[4];
  const float* Wk = (const float*)d_in[5];
  const float* bk = (const float*)d_in[6];
  const float* Wv = (const float*)d_in[7];
  const float* bv = (const float*)d_in[8];
  const float* We = (const float*)d_in[9];
  const float* be = (const float*)d_in[10];
  const float* Wo = (const float*)d_in[11];
  const float* bo = (const float*)d_in[12];
  float* out = (float*)d_out;

  const int* src = ei;             // edge_index[0]
  const int* dst = ei + N_EDGES;   // edge_index[1]

  // workspace layout (floats): q | k | v | scores  = 3*N*128 + E*4 ~ 89.6 MB
  float* q      = (float*)d_ws;
  float* k      = q + (long)N_NODES * HU;
  float* v      = k + (long)N_NODES * HU;
  float* scores = v + (long)N_NODES * HU;

  qkv_kernel<<<N_NODES / NPB, 128, 0, stream>>>(x, Wq, bq, Wk, bk, Wv, bv, q, k, v);
  score_kernel<<<N_EDGES / EPB, 128, 0, stream>>>(ef, src, dst, We, be, q, k, scores);
  aggregate_kernel<<<N_NODES, 128, 0, stream>>>(src, dst, scores, v, Wo, bo, out);
}

// Round 2
// 669.381 us; speedup vs baseline: 1.3123x; 1.3123x over previous
//
#include <hip/hip_runtime.h>
#include <math.h>

#define N_NODES 50000
#define N_EDGES 800000
#define D_IN    128
#define ED_IN   64
#define HU      128   // H*U
#define NH      4
#define UD      32

#define NPB 8    // nodes per block in qkv kernel
#define GPB 8    // nodes per block in g kernel
#define EPB 16   // edges per block in score kernel

// K0: segment offsets from sorted src. off[n] = lower_bound(src, n); off[N] = E.
__global__ __launch_bounds__(256) void offsets_kernel(
    const int* __restrict__ src, int* __restrict__ off) {
  const int e = blockIdx.x * 256 + threadIdx.x;
  if (e >= N_EDGES) return;
  const int s = src[e];
  const int prev = (e == 0) ? -1 : src[e - 1];
  for (int n = prev + 1; n <= s; ++n) off[n] = e;
  if (e == N_EDGES - 1)
    for (int n = s + 1; n <= N_NODES; ++n) off[n] = N_EDGES;
}

// K1: q/k/v projections. q stores (x@Wq + bq + be) so the be.k score term is free.
__global__ __launch_bounds__(128) void qkv_kernel(
    const float* __restrict__ x,
    const float* __restrict__ Wq, const float* __restrict__ bq,
    const float* __restrict__ Wk, const float* __restrict__ bk,
    const float* __restrict__ Wv, const float* __restrict__ bv,
    const float* __restrict__ be,
    float* __restrict__ q, float* __restrict__ k, float* __restrict__ v) {
  const int base = blockIdx.x * NPB;
  const int t = threadIdx.x;
  __shared__ float xs[NPB][D_IN];
  for (int j = 0; j < NPB; ++j)
    xs[j][t] = x[(long)(base + j) * D_IN + t];
  __syncthreads();
  float aq[NPB], ak[NPB], av[NPB];
  const float bqt = bq[t] + be[t], bkt = bk[t], bvt = bv[t];
  for (int j = 0; j < NPB; ++j) { aq[j] = bqt; ak[j] = bkt; av[j] = bvt; }
  for (int i = 0; i < D_IN; ++i) {
    const float wq = Wq[i * HU + t];
    const float wk = Wk[i * HU + t];
    const float wv = Wv[i * HU + t];
    for (int j = 0; j < NPB; ++j) {
      const float xi = xs[j][i];
      aq[j] += xi * wq; ak[j] += xi * wk; av[j] += xi * wv;
    }
  }
  for (int j = 0; j < NPB; ++j) {
    const long o = (long)(base + j) * HU + t;
    q[o] = aq[j]; k[o] = ak[j]; v[o] = av[j];
  }
}

// K1b: g[n, h, i] = sum_u We[i, h*32+u] * k[n, h*32+u]   (g is [N, 4, 64])
__global__ __launch_bounds__(128) void gmat_kernel(
    const float* __restrict__ k, const float* __restrict__ We,
    float* __restrict__ g) {
  const int base = blockIdx.x * GPB;
  const int t = threadIdx.x;
  __shared__ float ks[GPB][HU];
  for (int j = 0; j < GPB; ++j)
    ks[j][t] = k[(long)(base + j) * HU + t];
  __syncthreads();
  for (int r = 0; r < 2; ++r) {
    const int o = t + 128 * r;      // output index in [0,256)
    const int h = o >> 6, i = o & 63;
    float acc[GPB];
    for (int j = 0; j < GPB; ++j) acc[j] = 0.f;
    for (int u = 0; u < 32; ++u) {
      const float w = We[i * HU + h * 32 + u];
      for (int j = 0; j < GPB; ++j) acc[j] += w * ks[j][h * 32 + u];
    }
    for (int j = 0; j < GPB; ++j)
      g[(long)(base + j) * 256 + o] = acc[j];
  }
}

// K2: scores[e,h] = sum_u q'[s,h,u]*k[d,h,u] + sum_i ef[e,i]*g[d,h,i]
__global__ __launch_bounds__(128) void score_kernel(
    const float* __restrict__ ef,
    const int* __restrict__ src, const int* __restrict__ dst,
    const float* __restrict__ q, const float* __restrict__ k,
    const float* __restrict__ g,
    float* __restrict__ scores) {
  const long base = (long)blockIdx.x * EPB;
  const int t = threadIdx.x;
  const int h = t >> 5, ul = t & 31;
  __shared__ float efs[EPB][ED_IN];
  for (int r = 0; r < EPB; r += 2) {
    const int row = r + (t >> 6);
    const int col = t & 63;
    efs[row][col] = ef[(base + row) * ED_IN + col];
  }
  __syncthreads();
  // stage the block's edge endpoints in registers (lane&15 holds edge base+lane&15)
  const int ss = src[base + (t & 15)];
  const int dd = dst[base + (t & 15)];
  for (int j = 0; j < EPB; ++j) {
    const int s = __shfl(ss, j, 16);
    const int d = __shfl(dd, j, 16);
    float p = q[(long)s * HU + t] * k[(long)d * HU + t];
    const float* gd = g + (long)d * 256 + h * 64;
    p += efs[j][ul] * gd[ul];
    p += efs[j][ul + 32] * gd[ul + 32];
    for (int off = 16; off > 0; off >>= 1) p += __shfl_down(p, off, 32);
    if (ul == 0) scores[(base + j) * NH + h] = p;
  }
}

// K3: segmented softmax + attn*v aggregation + output GEMM + relu.
// One block (128 thr) per node; thread t -> (h = t>>5, u = t&31).
__global__ __launch_bounds__(128) void aggregate_kernel(
    const int* __restrict__ off, const int* __restrict__ dst,
    const float* __restrict__ scores, const float* __restrict__ v,
    const float* __restrict__ Wo, const float* __restrict__ bo,
    float* __restrict__ out) {
  const int n = blockIdx.x;
  const int t = threadIdx.x;
  const int h = t >> 5, ul = t & 31;
  const int start = off[n], end = off[n + 1];

  float m = -INFINITY, l = 0.f, acc = 0.f;
  for (int cs = start; cs < end; cs += 32) {
    const int ce = min(cs + 32, end);
    const int e = cs + ul;
    const bool live = (e < ce);
    float sc = live ? scores[(long)e * NH + h] : -INFINITY;
    int dl = live ? dst[e] : 0;
    // chunk max (butterfly -> all lanes)
    float mc = sc;
    for (int o = 16; o > 0; o >>= 1) mc = fmaxf(mc, __shfl_xor(mc, o, 32));
    const float nm = fmaxf(m, mc);
    const float w = __expf(sc - nm);       // 0 for dead lanes
    const float corr = __expf(m - nm);     // 0 on first chunk
    float ws = w;
    for (int o = 16; o > 0; o >>= 1) ws += __shfl_xor(ws, o, 32);
    l = l * corr + ws;
    acc *= corr;
    m = nm;
    const int cnt = ce - cs;
    for (int j = 0; j < cnt; ++j) {
      const float wj = __shfl(w, j, 32);
      const int dj = __shfl(dl, j, 32);
      acc += wj * v[(long)dj * HU + t];
    }
  }
  const float inv = (l > 0.f) ? 1.f / l : 0.f;
  acc *= inv;

  __shared__ float att[HU];
  __shared__ float part[HU];
  att[t] = acc;
  __syncthreads();
  // out[n,o] = relu(sum_f att[f]*Wo[f,o] + bo[o]); 4 partial slices then reduce
  const int o = t & 31, fs = t >> 5;
  float po = 0.f;
  for (int j = 0; j < 32; ++j)
    po += att[fs * 32 + j] * Wo[(fs * 32 + j) * UD + o];
  part[t] = po;
  __syncthreads();
  if (t < UD) {
    const float oo = part[t] + part[t + 32] + part[t + 64] + part[t + 96] + bo[t];
    out[(long)n * UD + t] = fmaxf(oo, 0.f);
  }
}

extern "C" void kernel_launch(void* const* d_in, const int* in_sizes, int n_in,
                              void* d_out, int out_size, void* d_ws, size_t ws_size,
                              hipStream_t stream) {
  const float* x  = (const float*)d_in[0];
  const int*   ei = (const int*)d_in[1];
  const float* ef = (const float*)d_in[2];
  const float* Wq = (const float*)d_in[3];
  const float* bq = (const float*)d_in[4];
  const float* Wk = (const float*)d_in[5];
  const float* bk = (const float*)d_in[6];
  const float* Wv = (const float*)d_in[7];
  const float* bv = (const float*)d_in[8];
  const float* We = (const float*)d_in[9];
  const float* be = (const float*)d_in[10];
  const float* Wo = (const float*)d_in[11];
  const float* bo = (const float*)d_in[12];
  float* out = (float*)d_out;

  const int* src = ei;             // edge_index[0]
  const int* dst = ei + N_EDGES;   // edge_index[1]

  // ws layout (floats): q | k | v | g | scores | off
  float* q      = (float*)d_ws;
  float* k      = q + (long)N_NODES * HU;
  float* v      = k + (long)N_NODES * HU;
  float* g      = v + (long)N_NODES * HU;
  float* scores = g + (long)N_NODES * 256;
  int*   off    = (int*)(scores + (long)N_EDGES * NH);

  offsets_kernel<<<(N_EDGES + 255) / 256, 256, 0, stream>>>(src, off);
  qkv_kernel<<<N_NODES / NPB, 128, 0, stream>>>(x, Wq, bq, Wk, bk, Wv, bv, be, q, k, v);
  gmat_kernel<<<N_NODES / GPB, 128, 0, stream>>>(k, We, g);
  score_kernel<<<N_EDGES / EPB, 128, 0, stream>>>(ef, src, dst, q, k, g, scores);
  aggregate_kernel<<<N_NODES, 128, 0, stream>>>(off, dst, scores, v, Wo, bo, out);
}